// Round 3
// baseline (449.346 us; speedup 1.0000x reference)
//
#include <hip/hip_runtime.h>
#include <math.h>

#define N_   8
#define C_   64
#define H_   128
#define W_   128
#define HW_  (H_ * W_)
#define CHW_ (C_ * HW_)
#define K_   3
#define CI_TILE 4
#define CO_BLK  16              // co channels per block
#define N_CG    (C_ / CO_BLK)   // 4 co-groups
#define TILE 16
#define HALO (TILE + 2)          // 18
// Row stride 48 floats == 16 (mod 32): a wave's 4 rows x 16 cols map exactly
// 2 lanes/bank (rows 0,2 -> banks b..b+15; rows 1,3 -> b+16..b+31). 2-way is
// free on CDNA4 (m136); the old stride-19 layout had 3-way collisions (10.8M
// conflict cycles measured).
#define XSTRIDE 48
#define WSTRIDE (C_ * K_ * K_)   // 576 floats between consecutive co's
#define BN_EPS 1e-5
#define POW_EPS 1e-12f

// Kernel 1: y[n,co,h,w] = -sum_{ci,kh,kw} |x[n,ci,h+kh-1,w+kw-1] - W[co,ci,kh,kw]| + x[n,co,h,w]
// launch_bounds(256,6): 85-VGPR cap so acc[16] stays VGPR-resident. Under the
// previous (256,8)/64-VGPR cap the compiler evicted acc to AGPRs (VGPR_Count
// was 20 < |acc|+|xv|), paying extra VALU per term -> ~2.2x issue bloat vs the
// 2-op/term floor. 6 blocks/CU = 24 waves (75%) vs measured 67% before.
__global__ __launch_bounds__(256, 6) void adder_kernel(
    const float* __restrict__ x, const float* __restrict__ weight,
    float* __restrict__ y, double* __restrict__ sums)
{
    __shared__ float sx[CI_TILE][HALO][XSTRIDE];      // 4*18*48*4 = 13824 B
    __shared__ float red[CO_BLK][2][4];               // per-wave stat partials

    const int tx = threadIdx.x & 15;
    const int ty = threadIdx.x >> 4;
    const int tile_h = blockIdx.x >> 3;   // H_/TILE = 8 tiles
    const int tile_w = blockIdx.x & 7;    // W_/TILE = 8 tiles
    const int n   = blockIdx.y;
    const int co0 = blockIdx.z * CO_BLK;
    const int h0 = tile_h * TILE;
    const int w0 = tile_w * TILE;

    float acc[CO_BLK];
#pragma unroll
    for (int j = 0; j < CO_BLK; ++j) acc[j] = 0.f;

    const float* xn = x + n * CHW_;

    for (int cb = 0; cb < C_; cb += CI_TILE) {
        __syncthreads();  // protect previous chunk's reads before overwrite
        // Stage CI_TILE x 18 x 18 halo tile, zero-filled outside image.
        for (int idx = threadIdx.x; idx < CI_TILE * HALO * HALO; idx += 256) {
            int ci  = idx / (HALO * HALO);
            int rem = idx - ci * (HALO * HALO);
            int r   = rem / HALO;
            int cc  = rem - r * HALO;
            int gh  = h0 + r - 1;
            int gw  = w0 + cc - 1;
            float v = 0.f;
            if ((unsigned)gh < (unsigned)H_ && (unsigned)gw < (unsigned)W_)
                v = xn[(cb + ci) * HW_ + gh * W_ + gw];
            sx[ci][r][cc] = v;
        }
        __syncthreads();

        // Fully unrolled ci: one big scheduling window so ds_reads and the
        // wave-uniform weight s_loads pipeline across iterations.
#pragma unroll
        for (int ci = 0; ci < CI_TILE; ++ci) {
            float xv[9];
#pragma unroll
            for (int kh = 0; kh < 3; ++kh)
#pragma unroll
                for (int kw = 0; kw < 3; ++kw)
                    xv[kh * 3 + kw] = sx[ci][ty + kh][tx + kw];

            // Wave-uniform weight pointer -> scalar loads (SMEM broadcast).
            const float* wp = weight + co0 * WSTRIDE + (cb + ci) * (K_ * K_);
#pragma unroll
            for (int j = 0; j < CO_BLK; ++j) {
                const float* wc = wp + j * WSTRIDE;
#pragma unroll
                for (int k = 0; k < 9; ++k)
                    acc[j] += fabsf(xv[k] - wc[k]);
            }
        }
    }

    // Epilogue: y = -acc + residual x; fused per-channel sum/sumsq for BN.
    const int pix = (h0 + ty) * W_ + (w0 + tx);
    float* yo = y + n * CHW_ + co0 * HW_ + pix;
    const float* xr = xn + co0 * HW_ + pix;
    const int lane = threadIdx.x & 63;
    const int wid  = threadIdx.x >> 6;

#pragma unroll
    for (int j = 0; j < CO_BLK; ++j) {
        float v = -acc[j] + xr[j * HW_];
        yo[j * HW_] = v;
        float s = v, ss = v * v;
#pragma unroll
        for (int off = 32; off > 0; off >>= 1) {
            s  += __shfl_down(s, off);
            ss += __shfl_down(ss, off);
        }
        if (lane == 0) { red[j][0][wid] = s; red[j][1][wid] = ss; }
    }
    __syncthreads();
    if (threadIdx.x < CO_BLK) {
        int j = threadIdx.x;
        float S  = red[j][0][0] + red[j][0][1] + red[j][0][2] + red[j][0][3];
        float SS = red[j][1][0] + red[j][1][1] + red[j][1][2] + red[j][1][3];
        atomicAdd(&sums[co0 + j], (double)S);
        atomicAdd(&sums[C_ + co0 + j], (double)SS);
    }
}

// Kernel 3: per-channel scale/shift from batch stats.
__global__ void finalize_kernel(const double* __restrict__ sums,
                                const float* __restrict__ gamma,
                                const float* __restrict__ beta,
                                float* __restrict__ sc)
{
    const int c = threadIdx.x;  // 64 threads
    const double cnt = (double)(N_ * HW_);
    double mean = sums[c] / cnt;
    double var  = sums[C_ + c] / cnt - mean * mean;
    float inv   = (float)(1.0 / sqrt(var + (double)BN_EPS));
    float scale = gamma[c] * inv;
    float shift = beta[c] - (float)mean * scale;
    sc[c]      = scale;
    sc[C_ + c] = shift;
}

// Kernel 4: in-place BN affine + power activation, float4 vectorized.
// alpha==1 fast path (wave-uniform branch): sign(t)*(|t|+1e-12)^1 = t +- 1e-12,
// far below tolerance -> skip the powf expansion entirely.
__global__ __launch_bounds__(256) void apply_kernel(
    float* __restrict__ y, const float* __restrict__ sc,
    const float* __restrict__ alpha_p)
{
    const int idx = blockIdx.x * 256 + threadIdx.x;   // float4 index
    const float alpha = alpha_p[0];
    const int e0 = idx * 4;
    const int c = (e0 / HW_) & (C_ - 1);   // HW_ divisible by 4: all 4 in same channel
    const float scale = sc[c];
    const float shift = sc[C_ + c];

    float4 v = reinterpret_cast<float4*>(y)[idx];
    float* pv = reinterpret_cast<float*>(&v);
    if (alpha == 1.0f) {
#pragma unroll
        for (int i = 0; i < 4; ++i)
            pv[i] = pv[i] * scale + shift;
    } else {
#pragma unroll
        for (int i = 0; i < 4; ++i) {
            float t = pv[i] * scale + shift;
            float sgn = (t > 0.f) ? 1.f : ((t < 0.f) ? -1.f : 0.f);
            pv[i] = sgn * powf(fabsf(t) + POW_EPS, alpha);
        }
    }
    reinterpret_cast<float4*>(y)[idx] = v;
}

extern "C" void kernel_launch(void* const* d_in, const int* in_sizes, int n_in,
                              void* d_out, int out_size, void* d_ws, size_t ws_size,
                              hipStream_t stream)
{
    const float* x      = (const float*)d_in[0];
    const float* weight = (const float*)d_in[1];
    const float* gamma  = (const float*)d_in[2];
    const float* beta   = (const float*)d_in[3];
    const float* alpha  = (const float*)d_in[4];
    float* out = (float*)d_out;

    double* sums = (double*)d_ws;                                // 128 doubles
    float*  sc   = (float*)((char*)d_ws + 128 * sizeof(double)); // 128 floats

    hipMemsetAsync(d_ws, 0, 128 * sizeof(double), stream);

    adder_kernel<<<dim3(64, N_, N_CG), 256, 0, stream>>>(x, weight, out, sums);
    finalize_kernel<<<1, C_, 0, stream>>>(sums, gamma, beta, sc);

    const int n4 = (N_ * CHW_) / 4;           // 2,097,152 float4s
    apply_kernel<<<n4 / 256, 256, 0, stream>>>(out, sc, alpha);
}

// Round 4
// 413.829 us; speedup vs baseline: 1.0858x; 1.0858x over previous
//
#include <hip/hip_runtime.h>
#include <math.h>

#define N_   8
#define C_   64
#define H_   128
#define W_   128
#define HW_  (H_ * W_)
#define CHW_ (C_ * HW_)
#define K_   3
#define CI_TILE 8
#define CO_BLK  8               // co channels per block (72 weight floats/ci -> fits SGPRs)
#define N_CG    (C_ / CO_BLK)   // 8 co-groups
#define TILE 16
#define HALO (TILE + 2)          // 18
// Row stride 24 floats == 24 (mod 32): consecutive rows' bank windows rotate
// by 24, so the wave's 4 rows x 16 cols land exactly 2 lanes/bank for every
// kw shift -- 2-way is free on CDNA4 (m136). Verified direction in R3:
// stride-48 (also uniform 2-way) cut SQ_LDS_BANK_CONFLICT 10.8M -> 1.3M.
// Stride 24 gets the same property at HALF the LDS: 8*18*24*4 = 13824 B
// -> 8 blocks/CU LDS-feasible (110 KB of 160 KB).
#define XSTRIDE 24
#define WSTRIDE (C_ * K_ * K_)   // 576 floats between consecutive co's
#define BN_EPS 1e-5
#define POW_EPS 1e-12f

// Kernel 1: y[n,co,h,w] = -sum_{ci,kh,kw} |x[n,ci,h+kh-1,w+kw-1] - W[co,ci,kh,kw]| + x[n,co,h,w]
// CO_BLK=8: per-ci weight slice is 8*9=72 floats -> the whole slice fits in
// SGPRs (R2's 16*9=144 exceeded the ~100 usable and forced chunked
// s_load+wait inside the MAC stream). acc[8]+xv[9] ~ 35 VGPR fits the
// (256,8) 64-VGPR cap without AGPR eviction. Grid 4096 blocks, 8 blocks/CU.
__global__ __launch_bounds__(256, 8) void adder_kernel(
    const float* __restrict__ x, const float* __restrict__ weight,
    float* __restrict__ y, double* __restrict__ sums)
{
    __shared__ float sx[CI_TILE][HALO][XSTRIDE];      // 13824 B
    __shared__ float red[CO_BLK][2][4];               // per-wave stat partials

    const int tx = threadIdx.x & 15;
    const int ty = threadIdx.x >> 4;
    const int tile_h = blockIdx.x >> 3;   // H_/TILE = 8 tiles
    const int tile_w = blockIdx.x & 7;    // W_/TILE = 8 tiles
    const int n   = blockIdx.y;
    const int co0 = blockIdx.z * CO_BLK;
    const int h0 = tile_h * TILE;
    const int w0 = tile_w * TILE;

    float acc[CO_BLK];
#pragma unroll
    for (int j = 0; j < CO_BLK; ++j) acc[j] = 0.f;

    const float* xn = x + n * CHW_;

    for (int cb = 0; cb < C_; cb += CI_TILE) {
        __syncthreads();  // protect previous chunk's reads before overwrite
        // Stage CI_TILE x 18 x 18 halo tile, zero-filled outside image.
        for (int idx = threadIdx.x; idx < CI_TILE * HALO * HALO; idx += 256) {
            int ci  = idx / (HALO * HALO);
            int rem = idx - ci * (HALO * HALO);
            int r   = rem / HALO;
            int cc  = rem - r * HALO;
            int gh  = h0 + r - 1;
            int gw  = w0 + cc - 1;
            float v = 0.f;
            if ((unsigned)gh < (unsigned)H_ && (unsigned)gw < (unsigned)W_)
                v = xn[(cb + ci) * HW_ + gh * W_ + gw];
            sx[ci][r][cc] = v;
        }
        __syncthreads();

#pragma unroll 1
        for (int ci = 0; ci < CI_TILE; ++ci) {
            float xv[9];
#pragma unroll
            for (int kh = 0; kh < 3; ++kh)
#pragma unroll
                for (int kw = 0; kw < 3; ++kw)
                    xv[kh * 3 + kw] = sx[ci][ty + kh][tx + kw];

            // Wave-uniform weight pointer -> scalar loads (SGPR broadcast);
            // whole 72-float ci-slice fits in SGPRs.
            const float* wp = weight + co0 * WSTRIDE + (cb + ci) * (K_ * K_);
#pragma unroll
            for (int j = 0; j < CO_BLK; ++j) {
                const float* wc = wp + j * WSTRIDE;
#pragma unroll
                for (int k = 0; k < 9; ++k)
                    acc[j] += fabsf(xv[k] - wc[k]);
            }
        }
    }

    // Epilogue: y = -acc + residual x; fused per-channel sum/sumsq for BN.
    const int pix = (h0 + ty) * W_ + (w0 + tx);
    float* yo = y + n * CHW_ + co0 * HW_ + pix;
    const float* xr = xn + co0 * HW_ + pix;
    const int lane = threadIdx.x & 63;
    const int wid  = threadIdx.x >> 6;

#pragma unroll
    for (int j = 0; j < CO_BLK; ++j) {
        float v = -acc[j] + xr[j * HW_];
        yo[j * HW_] = v;
        float s = v, ss = v * v;
#pragma unroll
        for (int off = 32; off > 0; off >>= 1) {
            s  += __shfl_down(s, off);
            ss += __shfl_down(ss, off);
        }
        if (lane == 0) { red[j][0][wid] = s; red[j][1][wid] = ss; }
    }
    __syncthreads();
    if (threadIdx.x < CO_BLK) {
        int j = threadIdx.x;
        float S  = red[j][0][0] + red[j][0][1] + red[j][0][2] + red[j][0][3];
        float SS = red[j][1][0] + red[j][1][1] + red[j][1][2] + red[j][1][3];
        atomicAdd(&sums[co0 + j], (double)S);
        atomicAdd(&sums[C_ + co0 + j], (double)SS);
    }
}

// Kernel 3: per-channel scale/shift from batch stats.
__global__ void finalize_kernel(const double* __restrict__ sums,
                                const float* __restrict__ gamma,
                                const float* __restrict__ beta,
                                float* __restrict__ sc)
{
    const int c = threadIdx.x;  // 64 threads
    const double cnt = (double)(N_ * HW_);
    double mean = sums[c] / cnt;
    double var  = sums[C_ + c] / cnt - mean * mean;
    float inv   = (float)(1.0 / sqrt(var + (double)BN_EPS));
    float scale = gamma[c] * inv;
    float shift = beta[c] - (float)mean * scale;
    sc[c]      = scale;
    sc[C_ + c] = shift;
}

// Kernel 4: in-place BN affine + power activation, float4 vectorized.
// alpha==1 fast path (wave-uniform branch): sign(t)*(|t|+1e-12)^1 = t +- 1e-12,
// far below tolerance -> skip the powf expansion entirely.
__global__ __launch_bounds__(256) void apply_kernel(
    float* __restrict__ y, const float* __restrict__ sc,
    const float* __restrict__ alpha_p)
{
    const int idx = blockIdx.x * 256 + threadIdx.x;   // float4 index
    const float alpha = alpha_p[0];
    const int e0 = idx * 4;
    const int c = (e0 / HW_) & (C_ - 1);   // HW_ divisible by 4: all 4 in same channel
    const float scale = sc[c];
    const float shift = sc[C_ + c];

    float4 v = reinterpret_cast<float4*>(y)[idx];
    float* pv = reinterpret_cast<float*>(&v);
    if (alpha == 1.0f) {
#pragma unroll
        for (int i = 0; i < 4; ++i)
            pv[i] = pv[i] * scale + shift;
    } else {
#pragma unroll
        for (int i = 0; i < 4; ++i) {
            float t = pv[i] * scale + shift;
            float sgn = (t > 0.f) ? 1.f : ((t < 0.f) ? -1.f : 0.f);
            pv[i] = sgn * powf(fabsf(t) + POW_EPS, alpha);
        }
    }
    reinterpret_cast<float4*>(y)[idx] = v;
}

extern "C" void kernel_launch(void* const* d_in, const int* in_sizes, int n_in,
                              void* d_out, int out_size, void* d_ws, size_t ws_size,
                              hipStream_t stream)
{
    const float* x      = (const float*)d_in[0];
    const float* weight = (const float*)d_in[1];
    const float* gamma  = (const float*)d_in[2];
    const float* beta   = (const float*)d_in[3];
    const float* alpha  = (const float*)d_in[4];
    float* out = (float*)d_out;

    double* sums = (double*)d_ws;                                // 128 doubles
    float*  sc   = (float*)((char*)d_ws + 128 * sizeof(double)); // 128 floats

    hipMemsetAsync(d_ws, 0, 128 * sizeof(double), stream);

    adder_kernel<<<dim3(64, N_, N_CG), 256, 0, stream>>>(x, weight, out, sums);
    finalize_kernel<<<1, C_, 0, stream>>>(sums, gamma, beta, sc);

    const int n4 = (N_ * CHW_) / 4;           // 2,097,152 float4s
    apply_kernel<<<n4 / 256, 256, 0, stream>>>(out, sc, alpha);
}

// Round 5
// 326.323 us; speedup vs baseline: 1.3770x; 1.2682x over previous
//
#include <hip/hip_runtime.h>
#include <math.h>

#define N_   8
#define C_   64
#define H_   128
#define W_   128
#define HW_  (H_ * W_)
#define CHW_ (C_ * HW_)
#define K_   3
#define CI_TILE 8
#define CO_BLK  8               // co channels per block
#define N_CG    (C_ / CO_BLK)   // 8 co-groups
#define TILE 16
#define HALO (TILE + 2)          // 18
// Row stride 24 floats: rows' bank windows rotate by 24 (mod 32) -> the wave's
// 4 rows x 16 cols land exactly 2 lanes/bank (free on CDNA4, m136), at half
// the LDS of stride-48. 8*18*24*4 = 13824 B -> 8 blocks/CU LDS-feasible.
#define XSTRIDE 24
#define WSTRIDE (C_ * K_ * K_)   // 576 floats between consecutive co's
#define BN_EPS 1e-5
#define POW_EPS 1e-12f

// One |x-w| accumulate in EXACTLY 2 VALU instructions:
//   v_sub_f32 t, s_w, v_x        (SGPR src0 legal in VOP2; |w-x| == |x-w|)
//   v_add_f32 acc, acc, |t|      (VOP3 abs source-modifier, no v_and)
// "+v" pins acc to an arch VGPR (R4's VGPR_Count=16 showed acc was evicted
// to AGPRs, paying accvgpr moves per term -> measured ~5.8 ops/term vs the
// 2-op floor). "s" pins the wave-uniform weight to an SGPR.
#define MAC_TERM(accv, wjk, xvk) do { float t_;                        \
    asm("v_sub_f32 %1, %2, %3\n\t"                                     \
        "v_add_f32 %0, %0, |%1|"                                       \
        : "+v"(accv), "=&v"(t_)                                        \
        : "s"(wjk), "v"(xvk));                                         \
  } while (0)

__global__ __launch_bounds__(256, 8) void adder_kernel(
    const float* __restrict__ x, const float* __restrict__ weight,
    float* __restrict__ y, double* __restrict__ sums)
{
    __shared__ float sx[CI_TILE][HALO][XSTRIDE];      // 13824 B
    __shared__ float red[CO_BLK][2][4];               // per-wave stat partials

    const int tx = threadIdx.x & 15;
    const int ty = threadIdx.x >> 4;
    const int tile_h = blockIdx.x >> 3;   // H_/TILE = 8 tiles
    const int tile_w = blockIdx.x & 7;    // W_/TILE = 8 tiles
    const int n   = blockIdx.y;
    const int co0 = blockIdx.z * CO_BLK;
    const int h0 = tile_h * TILE;
    const int w0 = tile_w * TILE;

    float acc[CO_BLK];
#pragma unroll
    for (int j = 0; j < CO_BLK; ++j) acc[j] = 0.f;

    const float* xn = x + n * CHW_;

    for (int cb = 0; cb < C_; cb += CI_TILE) {
        __syncthreads();  // protect previous chunk's reads before overwrite
        // Stage CI_TILE x 18 x 18 halo tile, zero-filled outside image.
        for (int idx = threadIdx.x; idx < CI_TILE * HALO * HALO; idx += 256) {
            int ci  = idx / (HALO * HALO);
            int rem = idx - ci * (HALO * HALO);
            int r   = rem / HALO;
            int cc  = rem - r * HALO;
            int gh  = h0 + r - 1;
            int gw  = w0 + cc - 1;
            float v = 0.f;
            if ((unsigned)gh < (unsigned)H_ && (unsigned)gw < (unsigned)W_)
                v = xn[(cb + ci) * HW_ + gh * W_ + gw];
            sx[ci][r][cc] = v;
        }
        __syncthreads();

#pragma unroll 1
        for (int ci = 0; ci < CI_TILE; ++ci) {
            float xv[9];
#pragma unroll
            for (int kh = 0; kh < 3; ++kh)
#pragma unroll
                for (int kw = 0; kw < 3; ++kw)
                    xv[kh * 3 + kw] = sx[ci][ty + kh][tx + kw];

            // Wave-uniform weight slice: 8 co x 9 taps = 72 floats, preloaded
            // into SGPRs (static indices, s_load batched per co).
            const float* wp = weight + co0 * WSTRIDE + (cb + ci) * (K_ * K_);
            float w_s[CO_BLK][9];
#pragma unroll
            for (int j = 0; j < CO_BLK; ++j)
#pragma unroll
                for (int k = 0; k < 9; ++k)
                    w_s[j][k] = wp[j * WSTRIDE + k];

#pragma unroll
            for (int j = 0; j < CO_BLK; ++j)
#pragma unroll
                for (int k = 0; k < 9; ++k)
                    MAC_TERM(acc[j], w_s[j][k], xv[k]);
        }
    }

    // Epilogue: y = -acc + residual x; fused per-channel sum/sumsq for BN.
    const int pix = (h0 + ty) * W_ + (w0 + tx);
    float* yo = y + n * CHW_ + co0 * HW_ + pix;
    const float* xr = xn + co0 * HW_ + pix;
    const int lane = threadIdx.x & 63;
    const int wid  = threadIdx.x >> 6;

#pragma unroll
    for (int j = 0; j < CO_BLK; ++j) {
        float v = -acc[j] + xr[j * HW_];
        yo[j * HW_] = v;
        float s = v, ss = v * v;
#pragma unroll
        for (int off = 32; off > 0; off >>= 1) {
            s  += __shfl_down(s, off);
            ss += __shfl_down(ss, off);
        }
        if (lane == 0) { red[j][0][wid] = s; red[j][1][wid] = ss; }
    }
    __syncthreads();
    if (threadIdx.x < CO_BLK) {
        int j = threadIdx.x;
        float S  = red[j][0][0] + red[j][0][1] + red[j][0][2] + red[j][0][3];
        float SS = red[j][1][0] + red[j][1][1] + red[j][1][2] + red[j][1][3];
        atomicAdd(&sums[co0 + j], (double)S);
        atomicAdd(&sums[C_ + co0 + j], (double)SS);
    }
}

// Per-channel scale/shift from batch stats.
__global__ void finalize_kernel(const double* __restrict__ sums,
                                const float* __restrict__ gamma,
                                const float* __restrict__ beta,
                                float* __restrict__ sc)
{
    const int c = threadIdx.x;  // 64 threads
    const double cnt = (double)(N_ * HW_);
    double mean = sums[c] / cnt;
    double var  = sums[C_ + c] / cnt - mean * mean;
    float inv   = (float)(1.0 / sqrt(var + (double)BN_EPS));
    float scale = gamma[c] * inv;
    float shift = beta[c] - (float)mean * scale;
    sc[c]      = scale;
    sc[C_ + c] = shift;
}

// In-place BN affine + power activation, float4 vectorized.
// alpha==1 fast path (wave-uniform branch): sign(t)*(|t|+1e-12)^1 = t +- 1e-12,
// far below tolerance -> skip the powf expansion entirely.
__global__ __launch_bounds__(256) void apply_kernel(
    float* __restrict__ y, const float* __restrict__ sc,
    const float* __restrict__ alpha_p)
{
    const int idx = blockIdx.x * 256 + threadIdx.x;   // float4 index
    const float alpha = alpha_p[0];
    const int e0 = idx * 4;
    const int c = (e0 / HW_) & (C_ - 1);   // HW_ divisible by 4: all 4 in same channel
    const float scale = sc[c];
    const float shift = sc[C_ + c];

    float4 v = reinterpret_cast<float4*>(y)[idx];
    float* pv = reinterpret_cast<float*>(&v);
    if (alpha == 1.0f) {
#pragma unroll
        for (int i = 0; i < 4; ++i)
            pv[i] = pv[i] * scale + shift;
    } else {
#pragma unroll
        for (int i = 0; i < 4; ++i) {
            float t = pv[i] * scale + shift;
            float sgn = (t > 0.f) ? 1.f : ((t < 0.f) ? -1.f : 0.f);
            pv[i] = sgn * powf(fabsf(t) + POW_EPS, alpha);
        }
    }
    reinterpret_cast<float4*>(y)[idx] = v;
}

extern "C" void kernel_launch(void* const* d_in, const int* in_sizes, int n_in,
                              void* d_out, int out_size, void* d_ws, size_t ws_size,
                              hipStream_t stream)
{
    const float* x      = (const float*)d_in[0];
    const float* weight = (const float*)d_in[1];
    const float* gamma  = (const float*)d_in[2];
    const float* beta   = (const float*)d_in[3];
    const float* alpha  = (const float*)d_in[4];
    float* out = (float*)d_out;

    double* sums = (double*)d_ws;                                // 128 doubles
    float*  sc   = (float*)((char*)d_ws + 128 * sizeof(double)); // 128 floats

    hipMemsetAsync(d_ws, 0, 128 * sizeof(double), stream);

    adder_kernel<<<dim3(64, N_, N_CG), 256, 0, stream>>>(x, weight, out, sums);
    finalize_kernel<<<1, C_, 0, stream>>>(sums, gamma, beta, sc);

    const int n4 = (N_ * CHW_) / 4;           // 2,097,152 float4s
    apply_kernel<<<n4 / 256, 256, 0, stream>>>(out, sc, alpha);
}

// Round 6
// 325.125 us; speedup vs baseline: 1.3821x; 1.0037x over previous
//
#include <hip/hip_runtime.h>
#include <math.h>

#define N_   8
#define C_   64
#define H_   128
#define W_   128
#define HW_  (H_ * W_)
#define CHW_ (C_ * HW_)
#define K_   3
#define CI_TILE 8
#define CO_BLK  16              // co channels per block (halves all non-MAC overhead vs 8)
#define N_CG    (C_ / CO_BLK)   // 4 co-groups
#define TILE 16
#define HALO (TILE + 2)          // 18
// Row stride 24 floats: rows' bank windows rotate by 24 (mod 32) -> the wave's
// 4 rows x 16 cols land exactly 2 lanes/bank (free on CDNA4, m136).
#define XSTRIDE 24
#define CISZ (HALO * XSTRIDE)    // floats per ci plane (432)
#define NSTG ((CI_TILE * HALO * HALO) / 256)        // 10 full staging rounds
#define STG_TAIL (CI_TILE * HALO * HALO - NSTG*256) // 32 tail elements
#define WSTRIDE (C_ * K_ * K_)   // 576 floats between consecutive co's
#define BN_EPS 1e-5
#define POW_EPS 1e-12f

// One |x-w| accumulate in EXACTLY 2 VALU instructions:
//   v_sub_f32 t, s_w, v_x        (SGPR src0 legal in VOP2; |w-x| == |x-w|)
//   v_add_f32 acc, acc, |t|      (VOP3 abs source-modifier)
#define MAC_TERM(accv, wjk, xvk) do { float t_;                        \
    asm("v_sub_f32 %1, %2, %3\n\t"                                     \
        "v_add_f32 %0, %0, |%1|"                                       \
        : "+v"(accv), "=&v"(t_)                                        \
        : "s"(wjk), "v"(xvk));                                         \
  } while (0)

__global__ __launch_bounds__(256, 8) void adder_kernel(
    const float* __restrict__ x, const float* __restrict__ weight,
    float* __restrict__ y, double* __restrict__ sums)
{
    __shared__ float sx[CI_TILE * CISZ];              // 13824 B
    __shared__ float red[CO_BLK][2][4];               // per-wave stat partials

    const int tx = threadIdx.x & 15;
    const int ty = threadIdx.x >> 4;
    const int tile_h = blockIdx.x >> 3;   // H_/TILE = 8 tiles
    const int tile_w = blockIdx.x & 7;    // W_/TILE = 8 tiles
    const int n   = blockIdx.y;
    const int co0 = blockIdx.z * CO_BLK;
    const int h0 = tile_h * TILE;
    const int w0 = tile_w * TILE;

    float acc[CO_BLK];
#pragma unroll
    for (int j = 0; j < CO_BLK; ++j) acc[j] = 0.f;

    const float* xn = x + n * CHW_;

    // Precompute staging offsets once (cb-independent): kills the per-chunk
    // magic-mul divisions that cost ~24 instr/element in earlier rounds.
    // g_off < 0 encodes "outside image -> zero-fill".
    int lds_off[NSTG], g_off[NSTG];
#pragma unroll
    for (int it = 0; it < NSTG; ++it) {
        int idx = threadIdx.x + it * 256;
        int ci  = idx / (HALO * HALO);
        int rem = idx - ci * (HALO * HALO);
        int r   = rem / HALO;
        int cc  = rem - r * HALO;
        int gh  = h0 + r - 1;
        int gw  = w0 + cc - 1;
        bool ok = ((unsigned)gh < (unsigned)H_) && ((unsigned)gw < (unsigned)W_);
        lds_off[it] = ci * CISZ + r * XSTRIDE + cc;
        g_off[it]   = ok ? (ci * HW_ + gh * W_ + gw) : -1;
    }
    int tail_lds = -1, tail_g = -1;
    if (threadIdx.x < STG_TAIL) {
        int idx = NSTG * 256 + threadIdx.x;
        int ci  = idx / (HALO * HALO);
        int rem = idx - ci * (HALO * HALO);
        int r   = rem / HALO;
        int cc  = rem - r * HALO;
        int gh  = h0 + r - 1;
        int gw  = w0 + cc - 1;
        bool ok = ((unsigned)gh < (unsigned)H_) && ((unsigned)gw < (unsigned)W_);
        tail_lds = ci * CISZ + r * XSTRIDE + cc;
        tail_g   = ok ? (ci * HW_ + gh * W_ + gw) : -1;
    }

    for (int cb = 0; cb < C_; cb += CI_TILE) {
        const float* xncb = xn + cb * HW_;
        __syncthreads();  // previous chunk fully read before overwrite
#pragma unroll
        for (int it = 0; it < NSTG; ++it) {
            float v = (g_off[it] >= 0) ? xncb[g_off[it]] : 0.f;
            sx[lds_off[it]] = v;
        }
        if (tail_lds >= 0) {
            float v = (tail_g >= 0) ? xncb[tail_g] : 0.f;
            sx[tail_lds] = v;
        }
        __syncthreads();

#pragma unroll 1
        for (int ci = 0; ci < CI_TILE; ++ci) {
            const float* sxc = &sx[ci * CISZ];
            float xv[9];
#pragma unroll
            for (int kh = 0; kh < 3; ++kh)
#pragma unroll
                for (int kw = 0; kw < 3; ++kw)
                    xv[kh * 3 + kw] = sxc[(ty + kh) * XSTRIDE + tx + kw];

            // Per-co weight slice (9 floats -> ~9 live SGPRs): compiler can
            // issue co j+1's s_loads during co j's MAC stream.
            const float* wp = weight + co0 * WSTRIDE + (cb + ci) * (K_ * K_);
#pragma unroll
            for (int j = 0; j < CO_BLK; ++j) {
                float wj[9];
#pragma unroll
                for (int k = 0; k < 9; ++k)
                    wj[k] = wp[j * WSTRIDE + k];
#pragma unroll
                for (int k = 0; k < 9; ++k)
                    MAC_TERM(acc[j], wj[k], xv[k]);
            }
        }
    }

    // Epilogue: y = -acc + residual x; fused per-channel sum/sumsq for BN.
    const int pix = (h0 + ty) * W_ + (w0 + tx);
    float* yo = y + n * CHW_ + co0 * HW_ + pix;
    const float* xr = xn + co0 * HW_ + pix;
    const int lane = threadIdx.x & 63;
    const int wid  = threadIdx.x >> 6;

#pragma unroll
    for (int j = 0; j < CO_BLK; ++j) {
        float v = -acc[j] + xr[j * HW_];
        yo[j * HW_] = v;
        float s = v, ss = v * v;
#pragma unroll
        for (int off = 32; off > 0; off >>= 1) {
            s  += __shfl_down(s, off);
            ss += __shfl_down(ss, off);
        }
        if (lane == 0) { red[j][0][wid] = s; red[j][1][wid] = ss; }
    }
    __syncthreads();
    if (threadIdx.x < CO_BLK) {
        int j = threadIdx.x;
        float S  = red[j][0][0] + red[j][0][1] + red[j][0][2] + red[j][0][3];
        float SS = red[j][1][0] + red[j][1][1] + red[j][1][2] + red[j][1][3];
        atomicAdd(&sums[co0 + j], (double)S);
        atomicAdd(&sums[C_ + co0 + j], (double)SS);
    }
}

// Per-channel scale/shift from batch stats.
__global__ void finalize_kernel(const double* __restrict__ sums,
                                const float* __restrict__ gamma,
                                const float* __restrict__ beta,
                                float* __restrict__ sc)
{
    const int c = threadIdx.x;  // 64 threads
    const double cnt = (double)(N_ * HW_);
    double mean = sums[c] / cnt;
    double var  = sums[C_ + c] / cnt - mean * mean;
    float inv   = (float)(1.0 / sqrt(var + (double)BN_EPS));
    float scale = gamma[c] * inv;
    float shift = beta[c] - (float)mean * scale;
    sc[c]      = scale;
    sc[C_ + c] = shift;
}

// In-place BN affine + power activation, float4 vectorized.
// alpha==1 fast path: sign(t)*(|t|+1e-12)^1 = t +- 1e-12 (below tolerance).
__global__ __launch_bounds__(256) void apply_kernel(
    float* __restrict__ y, const float* __restrict__ sc,
    const float* __restrict__ alpha_p)
{
    const int idx = blockIdx.x * 256 + threadIdx.x;   // float4 index
    const float alpha = alpha_p[0];
    const int e0 = idx * 4;
    const int c = (e0 / HW_) & (C_ - 1);   // HW_ divisible by 4: all 4 in same channel
    const float scale = sc[c];
    const float shift = sc[C_ + c];

    float4 v = reinterpret_cast<float4*>(y)[idx];
    float* pv = reinterpret_cast<float*>(&v);
    if (alpha == 1.0f) {
#pragma unroll
        for (int i = 0; i < 4; ++i)
            pv[i] = pv[i] * scale + shift;
    } else {
#pragma unroll
        for (int i = 0; i < 4; ++i) {
            float t = pv[i] * scale + shift;
            float sgn = (t > 0.f) ? 1.f : ((t < 0.f) ? -1.f : 0.f);
            pv[i] = sgn * powf(fabsf(t) + POW_EPS, alpha);
        }
    }
    reinterpret_cast<float4*>(y)[idx] = v;
}

extern "C" void kernel_launch(void* const* d_in, const int* in_sizes, int n_in,
                              void* d_out, int out_size, void* d_ws, size_t ws_size,
                              hipStream_t stream)
{
    const float* x      = (const float*)d_in[0];
    const float* weight = (const float*)d_in[1];
    const float* gamma  = (const float*)d_in[2];
    const float* beta   = (const float*)d_in[3];
    const float* alpha  = (const float*)d_in[4];
    float* out = (float*)d_out;

    double* sums = (double*)d_ws;                                // 128 doubles
    float*  sc   = (float*)((char*)d_ws + 128 * sizeof(double)); // 128 floats

    hipMemsetAsync(d_ws, 0, 128 * sizeof(double), stream);

    adder_kernel<<<dim3(64, N_, N_CG), 256, 0, stream>>>(x, weight, out, sums);
    finalize_kernel<<<1, C_, 0, stream>>>(sums, gamma, beta, sc);

    const int n4 = (N_ * CHW_) / 4;           // 2,097,152 float4s
    apply_kernel<<<n4 / 256, 256, 0, stream>>>(out, sc, alpha);
}